// Round 11
// baseline (731.764 us; speedup 1.0000x reference)
//
#include <hip/hip_runtime.h>
#include <cstdint>
#include <cstddef>

// ---------------- types / helpers ----------------
typedef __attribute__((ext_vector_type(4))) float f32x4;
typedef __attribute__((ext_vector_type(8))) unsigned short u16x8;
typedef __attribute__((ext_vector_type(4))) unsigned short u16x4;
typedef __bf16 bf16x8 __attribute__((ext_vector_type(8)));

__device__ __forceinline__ unsigned short f2bf(float f) {
  unsigned u = __builtin_bit_cast(unsigned, f);
  u += 0x7FFF + ((u >> 16) & 1);            // round-to-nearest-even
  return (unsigned short)(u >> 16);
}

__device__ __forceinline__ float bf2f(unsigned short u) {
  unsigned x = (unsigned)u << 16;
  return __builtin_bit_cast(float, x);
}

__device__ __forceinline__ void mfma16x16x32(f32x4& acc, u16x8 a, u16x8 b) {
  acc = __builtin_amdgcn_mfma_f32_16x16x32_bf16(
      __builtin_bit_cast(bf16x8, a), __builtin_bit_cast(bf16x8, b), acc, 0, 0, 0);
}

typedef __attribute__((address_space(1))) const unsigned int as1_u32;
typedef __attribute__((address_space(3))) unsigned int as3_u32;
__device__ __forceinline__ void load_lds16(const void* g, void* l) {
  __builtin_amdgcn_global_load_lds((as1_u32*)g, (as3_u32*)l, 16, 0, 0);
}

// log2(e)/sqrt(128)
#define QSCALE2 0.12751745f
#define GP_S 5242880                        // gemm1 partial stride (1024*5120)

__device__ __forceinline__ float gsum(const unsigned short* __restrict__ gp, size_t i) {
  return (bf2f(gp[i]) + bf2f(gp[i + GP_S])) +
         (bf2f(gp[i + 2 * (size_t)GP_S]) + bf2f(gp[i + 3 * (size_t)GP_S]));
}

// ---------------- kernel 1: fused converts + rope table (R10-identical) ----------
__global__ void k_cvt_all(const float* __restrict__ hs, const float* __restrict__ wq,
                          const float* __restrict__ wk, const float* __restrict__ wv,
                          const float* __restrict__ wo,
                          unsigned short* __restrict__ hs_bf, unsigned short* __restrict__ w_bf,
                          float2* __restrict__ tab) {
  const int total = 10616832;
  int stride = gridDim.x * blockDim.x;
  for (int i = blockIdx.x * blockDim.x + threadIdx.x; i < total; i += stride) {
    if (i >= 10485760) {                    // sincos table, 2048x64
      int j = i - 10485760;
      int t = j >> 6, f = j & 63;
      float inv = expf(-(float)f * 0.14391156831212787f);  // 10000^(-f/64)
      float ang = (float)t * inv;
      tab[j] = make_float2(cosf(ang), sinf(ang));
      continue;
    }
    const float4* src;
    unsigned short* dst;
    long j;
    if (i < 1048576) { src = (const float4*)hs; j = i; dst = hs_bf + (size_t)i * 4; }
    else {
      int t = i - 1048576;
      dst = w_bf + (size_t)t * 4;           // q|k|v|o packed contiguously
      if (t < 4194304)      { src = (const float4*)wq; j = t; }
      else if (t < 4718592) { src = (const float4*)wk; j = t - 4194304; }
      else if (t < 5242880) { src = (const float4*)wv; j = t - 4718592; }
      else                  { src = (const float4*)wo; j = t - 5242880; }
    }
    float4 v = src[j];
    u16x4 o = { f2bf(v.x), f2bf(v.y), f2bf(v.z), f2bf(v.w) };
    *(u16x4*)dst = o;
  }
}

// ---------------- kernel 2: GEMM1 (R10 core) + stream-K fused post epilogue ------
// All z-blocks write bf16 partials; last z-block per (x,y) tile (device-scope
// counter, G16 fences) re-reads 4 partials (L2/L3-hot) and runs the post work
// for its own 128x128 tile. Tile->work mapping: n0<4096: q-RoPE -> qr;
// 4096..4607: K head (n0-4096)/128 -> outk+kr (new rows 1024+m0.. AND past rows
// m0..); >=4608: V -> outv+vt (new + past). Replaces the k_post launch.
__global__ __launch_bounds__(256, 3) void k_gemm1_post(
    const unsigned short* __restrict__ A, const unsigned short* __restrict__ Bt,
    unsigned short* __restrict__ gp,
    const float* __restrict__ past, const float2* __restrict__ tab,
    float* __restrict__ outk, float* __restrict__ outv,
    unsigned short* __restrict__ kr, unsigned short* __restrict__ vt,
    unsigned short* __restrict__ qr, unsigned int* __restrict__ cnt) {
  const int M = 1024, N = 5120, K = 4096, KC = 1024;
  __shared__ unsigned short lA[2][128 * 32];
  __shared__ unsigned short lB[2][128 * 32];
  const int tid = threadIdx.x;
  const int w = tid >> 6, lane = tid & 63;
  const int wm = w >> 1, wn = w & 1;
  const int m0 = blockIdx.y * 128, n0 = blockIdx.x * 128;
  const int k0 = blockIdx.z * KC;
  const int lr = lane & 15, lg = lane >> 4;
  unsigned short* Cp = gp + (size_t)blockIdx.z * M * N;

  f32x4 acc[4][4];
#pragma unroll
  for (int i = 0; i < 4; i++)
#pragma unroll
    for (int j = 0; j < 4; j++) acc[i][j] = (f32x4){0.f, 0.f, 0.f, 0.f};

  const int srow = w * 32 + (lane >> 2);
  const int scol = (lane & 3) * 8;
  const unsigned short* gA = A + (size_t)(m0 + srow) * K + scol;
  const unsigned short* gB = Bt + (size_t)(n0 + srow) * K + scol;

  auto stage = [&](int buf, int kt) {
#pragma unroll
    for (int c = 0; c < 2; c++) {
      load_lds16(gA + (size_t)c * 16 * K + kt, &lA[buf][(w * 32 + c * 16) * 32]);
      load_lds16(gB + (size_t)c * 16 * K + kt, &lB[buf][(w * 32 + c * 16) * 32]);
    }
  };

  stage(0, k0);
  __syncthreads();
  int cur = 0;
  for (int kt = k0; kt < k0 + KC; kt += 32) {
    if (kt + 32 < k0 + KC) stage(cur ^ 1, kt + 32);
    u16x8 af[4], bf[4];
#pragma unroll
    for (int i = 0; i < 4; i++) af[i] = *(const u16x8*)&lA[cur][(wm * 64 + i * 16 + lr) * 32 + lg * 8];
#pragma unroll
    for (int j = 0; j < 4; j++) bf[j] = *(const u16x8*)&lB[cur][(wn * 64 + j * 16 + lr) * 32 + lg * 8];
#pragma unroll
    for (int i = 0; i < 4; i++)
#pragma unroll
      for (int j = 0; j < 4; j++) mfma16x16x32(acc[i][j], af[i], bf[j]);
    __syncthreads();
    cur ^= 1;
  }
#pragma unroll
  for (int i = 0; i < 4; i++)
#pragma unroll
    for (int j = 0; j < 4; j++)
#pragma unroll
      for (int r = 0; r < 4; r++) {
        int row = m0 + wm * 64 + i * 16 + lg * 4 + r;
        int col = n0 + wn * 64 + j * 16 + lr;
        Cp[(size_t)row * N + col] = f2bf(acc[i][j][r]);
      }

  // ---- stream-K handoff: release stores, count, last block proceeds ----
  __threadfence();                          // release partial stores (agent scope)
  __syncthreads();
  __shared__ unsigned int sflag;
  if (tid == 0) sflag = atomicAdd(&cnt[blockIdx.y * gridDim.x + blockIdx.x], 1u);
  __syncthreads();
  if (sflag != 3u) return;
  __threadfence();                          // acquire: see other XCDs' partials

  // ---- fused post epilogue for this tile ----
  if (n0 < 4096) {                          // Q: RoPE, pre-scaled, log2 domain
    const int h = n0 >> 7;
    for (int pass = 0; pass < 32; ++pass) {
      int flat = pass * 256 + tid;
      int d0 = flat & 63, row = flat >> 6;
      int q = m0 + row;
      size_t base = (size_t)q * 5120 + n0;
      float v1 = gsum(gp, base + d0), v2 = gsum(gp, base + d0 + 64);
      float2 cs = tab[(1024 + q) * 64 + d0];
      unsigned short* o = qr + ((size_t)h * 1024 + q) * 128;
      o[d0]      = f2bf((v1 * cs.x - v2 * cs.y) * QSCALE2);
      o[d0 + 64] = f2bf((v2 * cs.x + v1 * cs.y) * QSCALE2);
    }
  } else if (n0 < 4608) {                   // K: new rows + matching past rows
    const int h = (n0 - 4096) >> 7;
    for (int pass = 0; pass < 32; ++pass) {
      int flat = pass * 256 + tid;
      int d0 = flat & 63, row = flat >> 6;
      {                                     // new keys (pre-RoPE to outk, RoPE'd to kr)
        int t = 1024 + m0 + row;
        size_t base = (size_t)(m0 + row) * 5120 + n0;
        float v1 = gsum(gp, base + d0), v2 = gsum(gp, base + d0 + 64);
        float* o = outk + ((size_t)h * 2048 + t) * 128;
        o[d0] = v1; o[d0 + 64] = v2;
        float2 cs = tab[t * 64 + d0];
        unsigned short* ko = kr + ((size_t)h * 2048 + t) * 128;
        ko[d0]      = f2bf(v1 * cs.x - v2 * cs.y);
        ko[d0 + 64] = f2bf(v2 * cs.x + v1 * cs.y);
      }
      {                                     // past keys, rows m0..m0+127
        int t = m0 + row;
        const float* p = past + ((size_t)h * 1024 + t) * 128;
        float v1 = p[d0], v2 = p[d0 + 64];
        float* o = outk + ((size_t)h * 2048 + t) * 128;
        o[d0] = v1; o[d0 + 64] = v2;
        float2 cs = tab[t * 64 + d0];
        unsigned short* ko = kr + ((size_t)h * 2048 + t) * 128;
        ko[d0]      = f2bf(v1 * cs.x - v2 * cs.y);
        ko[d0 + 64] = f2bf(v2 * cs.x + v1 * cs.y);
      }
    }
  } else {                                  // V: new + past, plus [d][t] transpose
    const int h = (n0 - 4608) >> 7;
    for (int pass = 0; pass < 64; ++pass) {
      int flat = pass * 256 + tid;
      int d = flat & 127, row = flat >> 7;
      {
        int t = 1024 + m0 + row;
        float val = gsum(gp, (size_t)(m0 + row) * 5120 + n0 + d);
        outv[((size_t)h * 2048 + t) * 128 + d] = val;
        vt[((size_t)h * 128 + d) * 2048 + t] = f2bf(val);
      }
      {
        int t = m0 + row;
        float val = past[524288 + ((size_t)h * 1024 + t) * 128 + d];
        outv[((size_t)h * 2048 + t) * 128 + d] = val;
        vt[((size_t)h * 128 + d) * 2048 + t] = f2bf(val);
      }
    }
  }
}

// ---------------- kernel 3: flash attention, 8-wave shared-KV (R10-identical) ---
__global__ __launch_bounds__(512) void k_attn8(
    const unsigned short* __restrict__ qr,  // [32][1024][128] (pre-scaled, log2)
    const unsigned short* __restrict__ kr,  // [4][2048][128] (RoPE'd)
    const unsigned short* __restrict__ vt,  // [4][128][2048]
    unsigned short* __restrict__ ctxb) {    // [1024][4096] bf16
  __shared__ unsigned short k_lds[2][64 * 128];
  __shared__ unsigned short v_lds[2][128 * 64];
  __shared__ unsigned short plds[8][640];
  const int bid = blockIdx.x;
  const int h = bid >> 3;
  const int c = bid & 7;
  const int kvh = h >> 3;
  const int tid = threadIdx.x;
  const int w = tid >> 6, l = tid & 63;
  const int lr = l & 15, lg = l >> 4;
  const int q0 = c * 128 + w * 16;
  const unsigned short* kh = kr + (size_t)kvh * 2048 * 128;
  const unsigned short* vh = vt + (size_t)kvh * 128 * 2048;

  u16x8 qf[4];
  {
    const unsigned short* qb = qr + ((size_t)(h * 1024 + q0 + lr)) * 128 + lg * 8;
#pragma unroll
    for (int ks = 0; ks < 4; ks++) qf[ks] = *(const u16x8*)(qb + ks * 32);
  }
  f32x4 acc[8];
#pragma unroll
  for (int i = 0; i < 8; i++) acc[i] = (f32x4){0.f, 0.f, 0.f, 0.f};
  float m_r = -1e30f, l_r = 0.f;

  const int limit = 1024 + q0 + lr;
  const int mylimit = 1024 + q0 + 15;
  const int T = 18 + 2 * c;

  auto stageK = [&](int buf, int kb) {
#pragma unroll
    for (int i = 0; i < 2; i++) {
      int loff = i * 8192 + tid * 16;
      int row = loff >> 8;
      int scb = (loff & 255) ^ ((row & 7) << 4);
      load_lds16((const char*)(kh + (size_t)(kb + row) * 128) + scb,
                 (char*)&k_lds[buf][0] + loff);
    }
  };
  auto stageV = [&](int buf, int kb) {
#pragma unroll
    for (int i = 0; i < 2; i++) {
      int loff = i * 8192 + tid * 16;
      int row = loff >> 7;
      int scb = (loff & 127) ^ ((row & 7) << 4);
      load_lds16((const char*)(vh + (size_t)row * 2048 + kb) + scb,
                 (char*)&v_lds[buf][0] + loff);
    }
  };

  stageK(0, 0); stageV(0, 0);
  __syncthreads();
  int cur = 0;
  for (int t = 0; t < T; t++) {
    if (t + 1 < T) { stageK(cur ^ 1, (t + 1) * 64); stageV(cur ^ 1, (t + 1) * 64); }
    if (t * 64 <= mylimit) {
#pragma unroll
      for (int kc = 0; kc < 2; kc++) {
        const int kb = t * 64 + kc * 32;
        if (kb > mylimit) continue;
        f32x4 s[2];
#pragma unroll
        for (int sub = 0; sub < 2; sub++) {
          f32x4 a = (f32x4){0.f, 0.f, 0.f, 0.f};
          const int key = kc * 32 + sub * 16 + lr;
          const int swz = (key & 7) << 4;
#pragma unroll
          for (int ks = 0; ks < 4; ks++) {
            int addr = key * 256 + ((ks * 64 + lg * 16) ^ swz);
            u16x8 kf = *(const u16x8*)((const char*)&k_lds[cur][0] + addr);
            mfma16x16x32(a, kf, qf[ks]);
          }
          s[sub] = a;
        }
        float v[8];
#pragma unroll
        for (int r = 0; r < 4; r++) { v[r] = s[0][r]; v[4 + r] = s[1][r]; }
        if (kb + 31 > 1024 + q0) {
          const int kbase = kb + lg * 4;
#pragma unroll
          for (int r = 0; r < 4; r++) {
            if (kbase + r > limit)      v[r]     = -1e30f;
            if (kbase + 16 + r > limit) v[4 + r] = -1e30f;
          }
        }
        float tmax = v[0];
#pragma unroll
        for (int j = 1; j < 8; j++) tmax = fmaxf(tmax, v[j]);
        tmax = fmaxf(tmax, __shfl_xor(tmax, 16));
        tmax = fmaxf(tmax, __shfl_xor(tmax, 32));
        if (!__all(tmax <= m_r + 11.5f)) {
          float mn = fmaxf(m_r, tmax);
          float corr = exp2f(m_r - mn);
          m_r = mn;
          l_r *= corr;
#pragma unroll
          for (int nt = 0; nt < 8; nt++)
#pragma unroll
            for (int r = 0; r < 4; r++) acc[nt][r] *= corr;
        }
        float p[8];
        float psum = 0.f;
#pragma unroll
        for (int j = 0; j < 8; j++) { p[j] = exp2f(v[j] - m_r); psum += p[j]; }
        psum += __shfl_xor(psum, 16);
        psum += __shfl_xor(psum, 32);
        l_r += psum;
        unsigned wds[4];
#pragma unroll
        for (int j = 0; j < 4; j++) {
          unsigned lo = __builtin_bit_cast(unsigned, p[2 * j]) + 0x8000u;
          unsigned hi = __builtin_bit_cast(unsigned, p[2 * j + 1]) + 0x8000u;
          wds[j] = (hi & 0xFFFF0000u) | (lo >> 16);
        }
        char* pb = (char*)&plds[w][0] + lr * 80 + lg * 8;
        *(uint2*)(pb)      = make_uint2(wds[0], wds[1]);
        *(uint2*)(pb + 32) = make_uint2(wds[2], wds[3]);
        asm volatile("s_waitcnt lgkmcnt(0)" ::: "memory");
        u16x8 pf = *(const u16x8*)&plds[w][lr * 40 + lg * 8];
#pragma unroll
        for (int nt = 0; nt < 8; nt++) {
          const int d = nt * 16 + lr;
          int addr = d * 128 + ((kc * 64 + lg * 16) ^ ((d & 7) << 4));
          u16x8 vf = *(const u16x8*)((const char*)&v_lds[cur][0] + addr);
          mfma16x16x32(acc[nt], vf, pf);
        }
      }
    }
    __syncthreads();
    cur ^= 1;
  }
  float inv = 1.0f / l_r;
  unsigned short* ob = ctxb + (size_t)(q0 + lr) * 4096 + h * 128 + lg * 4;
#pragma unroll
  for (int nt = 0; nt < 8; nt++) {
    u16x4 o = { f2bf(acc[nt][0] * inv), f2bf(acc[nt][1] * inv),
                f2bf(acc[nt][2] * inv), f2bf(acc[nt][3] * inv) };
    *(u16x4*)(ob + nt * 16) = o;
  }
}

// ---------------- kernel 4: GEMM2 (R10 core) + stream-K fused reduce ------------
__global__ __launch_bounds__(256, 3) void k_gemm2_red(
    const unsigned short* __restrict__ A, const unsigned short* __restrict__ Bt,
    unsigned short* __restrict__ gp2, float* __restrict__ out_attn,
    unsigned int* __restrict__ cnt) {
  const int M = 1024, N = 4096, K = 4096, KC = 1024;
  __shared__ unsigned short lA[2][128 * 32];
  __shared__ unsigned short lB[2][128 * 32];
  const int tid = threadIdx.x;
  const int w = tid >> 6, lane = tid & 63;
  const int wm = w >> 1, wn = w & 1;
  const int m0 = blockIdx.y * 128, n0 = blockIdx.x * 128;
  const int k0 = blockIdx.z * KC;
  const int lr = lane & 15, lg = lane >> 4;
  unsigned short* Cp = gp2 + (size_t)blockIdx.z * M * N;

  f32x4 acc[4][4];
#pragma unroll
  for (int i = 0; i < 4; i++)
#pragma unroll
    for (int j = 0; j < 4; j++) acc[i][j] = (f32x4){0.f, 0.f, 0.f, 0.f};

  const int srow = w * 32 + (lane >> 2);
  const int scol = (lane & 3) * 8;
  const unsigned short* gA = A + (size_t)(m0 + srow) * K + scol;
  const unsigned short* gB = Bt + (size_t)(n0 + srow) * K + scol;

  auto stage = [&](int buf, int kt) {
#pragma unroll
    for (int c = 0; c < 2; c++) {
      load_lds16(gA + (size_t)c * 16 * K + kt, &lA[buf][(w * 32 + c * 16) * 32]);
      load_lds16(gB + (size_t)c * 16 * K + kt, &lB[buf][(w * 32 + c * 16) * 32]);
    }
  };

  stage(0, k0);
  __syncthreads();
  int cur = 0;
  for (int kt = k0; kt < k0 + KC; kt += 32) {
    if (kt + 32 < k0 + KC) stage(cur ^ 1, kt + 32);
    u16x8 af[4], bf[4];
#pragma unroll
    for (int i = 0; i < 4; i++) af[i] = *(const u16x8*)&lA[cur][(wm * 64 + i * 16 + lr) * 32 + lg * 8];
#pragma unroll
    for (int j = 0; j < 4; j++) bf[j] = *(const u16x8*)&lB[cur][(wn * 64 + j * 16 + lr) * 32 + lg * 8];
#pragma unroll
    for (int i = 0; i < 4; i++)
#pragma unroll
      for (int j = 0; j < 4; j++) mfma16x16x32(acc[i][j], af[i], bf[j]);
    __syncthreads();
    cur ^= 1;
  }
#pragma unroll
  for (int i = 0; i < 4; i++)
#pragma unroll
    for (int j = 0; j < 4; j++)
#pragma unroll
      for (int r = 0; r < 4; r++) {
        int row = m0 + wm * 64 + i * 16 + lg * 4 + r;
        int col = n0 + wn * 64 + j * 16 + lr;
        Cp[(size_t)row * N + col] = f2bf(acc[i][j][r]);
      }

  __threadfence();
  __syncthreads();
  __shared__ unsigned int sflag;
  if (tid == 0) sflag = atomicAdd(&cnt[blockIdx.y * gridDim.x + blockIdx.x], 1u);
  __syncthreads();
  if (sflag != 3u) return;
  __threadfence();

  const size_t S = (size_t)M * N;
  for (int pass = 0; pass < 16; ++pass) {
    int flat = pass * 256 + tid;            // float4 id within the 128x128 tile
    int row = flat >> 5, c4 = flat & 31;
    size_t idx = (size_t)(m0 + row) * 4096 + n0 + c4 * 4;
    const unsigned short* g = gp2 + idx;
    float4 o;
    o.x = (bf2f(g[0]) + bf2f(g[S])) + (bf2f(g[2 * S]) + bf2f(g[3 * S]));
    o.y = (bf2f(g[1]) + bf2f(g[1 + S])) + (bf2f(g[1 + 2 * S]) + bf2f(g[1 + 3 * S]));
    o.z = (bf2f(g[2]) + bf2f(g[2 + S])) + (bf2f(g[2 + 2 * S]) + bf2f(g[2 + 3 * S]));
    o.w = (bf2f(g[3]) + bf2f(g[3 + S])) + (bf2f(g[3 + 2 * S]) + bf2f(g[3 + 3 * S]));
    *(float4*)(out_attn + idx) = o;
  }
}

// ---------------- launch ----------------
extern "C" void kernel_launch(void* const* d_in, const int* in_sizes, int n_in,
                              void* d_out, int out_size, void* d_ws, size_t ws_size,
                              hipStream_t stream) {
  (void)in_sizes; (void)n_in; (void)out_size; (void)ws_size;
  const float* hs   = (const float*)d_in[0];
  const float* past = (const float*)d_in[1];
  // d_in[2] attention_mask: pure causal, synthesized analytically
  const float* Wq = (const float*)d_in[3];
  const float* Wk = (const float*)d_in[4];
  const float* Wv = (const float*)d_in[5];
  const float* Wo = (const float*)d_in[6];

  float* out_attn = (float*)d_out;                 // [1024][4096]
  float* out_pk = out_attn + 4194304;              // [4][2048][128]
  float* out_pv = out_pk + 1048576;                // [4][2048][128]

  const size_t MB = 1048576;
  char* ws = (char*)d_ws;
  unsigned short* hs_bf   = (unsigned short*)(ws);              // 8 MB
  unsigned short* wqkv_bf = (unsigned short*)(ws + 8 * MB);     // 40 MB [5120][4096]
  unsigned short* wo_bf   = (unsigned short*)(ws + 48 * MB);    // 32 MB [4096][4096]
  unsigned int*   cnt1    = (unsigned int*)(ws + 99 * MB);      // 320 ctr
  unsigned int*   cnt2    = cnt1 + 512;                         // 256 ctr
  float2*         tab     = (float2*)(ws + 100 * MB);           // 1 MB
  unsigned short* kr      = (unsigned short*)(ws + 101 * MB);   // 2 MB
  unsigned short* vt      = (unsigned short*)(ws + 103 * MB);   // 2 MB
  unsigned short* qr      = (unsigned short*)(ws + 105 * MB);   // 8 MB
  unsigned short* ctxb    = (unsigned short*)(ws + 113 * MB);   // 8 MB
  unsigned short* gp      = (unsigned short*)(ws + 128 * MB);   // 40 MB bf16 partials

  hipMemsetAsync(cnt1, 0, 8192, stream);           // zero stream-K counters

  k_cvt_all<<<2048, 256, 0, stream>>>(hs, Wq, Wk, Wv, Wo, hs_bf, wqkv_bf, tab);

  dim3 g1(5120 / 128, 1024 / 128, 4);              // 1280 blocks, 320 tiles
  k_gemm1_post<<<g1, 256, 0, stream>>>(hs_bf, wqkv_bf, gp, past, tab,
                                       out_pk, out_pv, kr, vt, qr, cnt1);

  k_attn8<<<256, 512, 0, stream>>>(qr, kr, vt, ctxb);

  dim3 g2(4096 / 128, 1024 / 128, 4);              // 1024 blocks, 256 tiles
  k_gemm2_red<<<g2, 256, 0, stream>>>(ctxb, wo_bf, gp, out_attn, cnt2);
}

// Round 12
// 253.962 us; speedup vs baseline: 2.8814x; 2.8814x over previous
//
#include <hip/hip_runtime.h>
#include <cstdint>
#include <cstddef>

// ---------------- types / helpers ----------------
typedef __attribute__((ext_vector_type(4))) float f32x4;
typedef __attribute__((ext_vector_type(8))) unsigned short u16x8;
typedef __attribute__((ext_vector_type(4))) unsigned short u16x4;
typedef __bf16 bf16x8 __attribute__((ext_vector_type(8)));

__device__ __forceinline__ unsigned short f2bf(float f) {
  unsigned u = __builtin_bit_cast(unsigned, f);
  u += 0x7FFF + ((u >> 16) & 1);            // round-to-nearest-even
  return (unsigned short)(u >> 16);
}

__device__ __forceinline__ float bf2f(unsigned short u) {
  unsigned x = (unsigned)u << 16;
  return __builtin_bit_cast(float, x);
}

__device__ __forceinline__ void mfma16x16x32(f32x4& acc, u16x8 a, u16x8 b) {
  acc = __builtin_amdgcn_mfma_f32_16x16x32_bf16(
      __builtin_bit_cast(bf16x8, a), __builtin_bit_cast(bf16x8, b), acc, 0, 0, 0);
}

typedef __attribute__((address_space(1))) const unsigned int as1_u32;
typedef __attribute__((address_space(3))) unsigned int as3_u32;
__device__ __forceinline__ void load_lds16(const void* g, void* l) {
  __builtin_amdgcn_global_load_lds((as1_u32*)g, (as3_u32*)l, 16, 0, 0);
}

// log2(e)/sqrt(128)
#define QSCALE2 0.12751745f
#define GP_S 5242880                        // gemm1 partial stride (1024*5120)

// vectorized 4-partial sum over 4 consecutive bf16 elements (8B-aligned)
__device__ __forceinline__ void gsum4(const unsigned short* __restrict__ gp,
                                      size_t i, float* o) {
  u16x4 a = *(const u16x4*)(gp + i);
  u16x4 b = *(const u16x4*)(gp + i + GP_S);
  u16x4 c = *(const u16x4*)(gp + i + 2 * (size_t)GP_S);
  u16x4 d = *(const u16x4*)(gp + i + 3 * (size_t)GP_S);
#pragma unroll
  for (int j = 0; j < 4; j++)
    o[j] = (bf2f(a[j]) + bf2f(b[j])) + (bf2f(c[j]) + bf2f(d[j]));
}

// ---------------- kernel 1: fused converts + rope table (R10-identical) ----------
__global__ void k_cvt_all(const float* __restrict__ hs, const float* __restrict__ wq,
                          const float* __restrict__ wk, const float* __restrict__ wv,
                          const float* __restrict__ wo,
                          unsigned short* __restrict__ hs_bf, unsigned short* __restrict__ w_bf,
                          float2* __restrict__ tab) {
  const int total = 10616832;
  int stride = gridDim.x * blockDim.x;
  for (int i = blockIdx.x * blockDim.x + threadIdx.x; i < total; i += stride) {
    if (i >= 10485760) {                    // sincos table, 2048x64
      int j = i - 10485760;
      int t = j >> 6, f = j & 63;
      float inv = expf(-(float)f * 0.14391156831212787f);  // 10000^(-f/64)
      float ang = (float)t * inv;
      tab[j] = make_float2(cosf(ang), sinf(ang));
      continue;
    }
    const float4* src;
    unsigned short* dst;
    long j;
    if (i < 1048576) { src = (const float4*)hs; j = i; dst = hs_bf + (size_t)i * 4; }
    else {
      int t = i - 1048576;
      dst = w_bf + (size_t)t * 4;           // q|k|v|o packed contiguously
      if (t < 4194304)      { src = (const float4*)wq; j = t; }
      else if (t < 4718592) { src = (const float4*)wk; j = t - 4194304; }
      else if (t < 5242880) { src = (const float4*)wv; j = t - 4718592; }
      else                  { src = (const float4*)wo; j = t - 5242880; }
    }
    float4 v = src[j];
    u16x4 o = { f2bf(v.x), f2bf(v.y), f2bf(v.z), f2bf(v.w) };
    *(u16x4*)dst = o;
  }
}

// ---------------- kernel 2: bf16 GEMM with split-K, bf16 partials (R10) ----------
__global__ __launch_bounds__(256) void k_gemm_bt(
    const unsigned short* __restrict__ A, const unsigned short* __restrict__ Bt,
    unsigned short* __restrict__ C, int M, int N, int K, int KC) {
  __shared__ unsigned short lA[2][128 * 32];
  __shared__ unsigned short lB[2][128 * 32];
  const int tid = threadIdx.x;
  const int w = tid >> 6, lane = tid & 63;
  const int wm = w >> 1, wn = w & 1;
  const int m0 = blockIdx.y * 128, n0 = blockIdx.x * 128;
  const int k0 = blockIdx.z * KC;
  const int lr = lane & 15, lg = lane >> 4;
  unsigned short* Cp = C + (size_t)blockIdx.z * M * N;

  f32x4 acc[4][4];
#pragma unroll
  for (int i = 0; i < 4; i++)
#pragma unroll
    for (int j = 0; j < 4; j++) acc[i][j] = (f32x4){0.f, 0.f, 0.f, 0.f};

  const int srow = w * 32 + (lane >> 2);
  const int scol = (lane & 3) * 8;
  const unsigned short* gA = A + (size_t)(m0 + srow) * K + scol;
  const unsigned short* gB = Bt + (size_t)(n0 + srow) * K + scol;

  auto stage = [&](int buf, int kt) {
#pragma unroll
    for (int c = 0; c < 2; c++) {
      load_lds16(gA + (size_t)c * 16 * K + kt, &lA[buf][(w * 32 + c * 16) * 32]);
      load_lds16(gB + (size_t)c * 16 * K + kt, &lB[buf][(w * 32 + c * 16) * 32]);
    }
  };

  stage(0, k0);
  __syncthreads();
  int cur = 0;
  for (int kt = k0; kt < k0 + KC; kt += 32) {
    if (kt + 32 < k0 + KC) stage(cur ^ 1, kt + 32);
    u16x8 af[4], bf[4];
#pragma unroll
    for (int i = 0; i < 4; i++) af[i] = *(const u16x8*)&lA[cur][(wm * 64 + i * 16 + lr) * 32 + lg * 8];
#pragma unroll
    for (int j = 0; j < 4; j++) bf[j] = *(const u16x8*)&lB[cur][(wn * 64 + j * 16 + lr) * 32 + lg * 8];
#pragma unroll
    for (int i = 0; i < 4; i++)
#pragma unroll
      for (int j = 0; j < 4; j++) mfma16x16x32(acc[i][j], af[i], bf[j]);
    __syncthreads();
    cur ^= 1;
  }
#pragma unroll
  for (int i = 0; i < 4; i++)
#pragma unroll
    for (int j = 0; j < 4; j++)
#pragma unroll
      for (int r = 0; r < 4; r++) {
        int row = m0 + wm * 64 + i * 16 + lg * 4 + r;
        int col = n0 + wn * 64 + j * 16 + lr;
        Cp[(size_t)row * N + col] = f2bf(acc[i][j][r]);
      }
}

// ---------------- kernel 3: split-K=4 reduce, bf16 partials -> f32 out (R10) ----
__global__ void k_reduce4(const u16x4* __restrict__ p, float4* __restrict__ out,
                          int n4, size_t stride4) {
  int stridet = gridDim.x * blockDim.x;
  for (int i = blockIdx.x * blockDim.x + threadIdx.x; i < n4; i += stridet) {
    u16x4 a = p[i], b = p[i + stride4], c = p[i + 2 * stride4], d = p[i + 3 * stride4];
    out[i] = make_float4((bf2f(a[0]) + bf2f(b[0])) + (bf2f(c[0]) + bf2f(d[0])),
                         (bf2f(a[1]) + bf2f(b[1])) + (bf2f(c[1]) + bf2f(d[1])),
                         (bf2f(a[2]) + bf2f(b[2])) + (bf2f(c[2]) + bf2f(d[2])),
                         (bf2f(a[3]) + bf2f(b[3])) + (bf2f(c[3]) + bf2f(d[3])));
  }
}

// ---------------- kernel 4: fused post, VECTORIZED + LDS-tiled V transpose ------
// grid 2688 x 256:
//   blocks [0,2048):    Q RoPE  — 32h x 1024q x 16 d-quads, u16x4 loads/stores
//   blocks [2048,2560):  K      — 4h x 2048t x 16 d-quads (past: float4 reads)
//   blocks [2560,2688):  V      — 4h x 32 t-tiles: 64t x 128d tile; outv float4
//                                 coalesced; vt transpose via LDS (u16x8 rows)
__global__ void k_post(const float* __restrict__ past, const unsigned short* __restrict__ gp,
                       float* __restrict__ outk, float* __restrict__ outv,
                       unsigned short* __restrict__ kr, unsigned short* __restrict__ vt,
                       unsigned short* __restrict__ qr, const float2* __restrict__ tab) {
  const int b = blockIdx.x;
  const int tid = threadIdx.x;
  if (b < 2048) {                           // ---- Q ----
    int flat = b * 256 + tid;
    int dq = (flat & 15) * 4;
    int q = (flat >> 4) & 1023;
    int h = flat >> 14;
    size_t base = (size_t)q * 5120 + h * 128;
    float v1[4], v2[4];
    gsum4(gp, base + dq, v1);
    gsum4(gp, base + 64 + dq, v2);
    u16x4 o1, o2;
#pragma unroll
    for (int j = 0; j < 4; j++) {
      float2 cs = tab[(1024 + q) * 64 + dq + j];
      o1[j] = f2bf((v1[j] * cs.x - v2[j] * cs.y) * QSCALE2);
      o2[j] = f2bf((v2[j] * cs.x + v1[j] * cs.y) * QSCALE2);
    }
    unsigned short* o = qr + ((size_t)h * 1024 + q) * 128;
    *(u16x4*)(o + dq) = o1;
    *(u16x4*)(o + 64 + dq) = o2;
  } else if (b < 2560) {                    // ---- K ----
    int flat = (b - 2048) * 256 + tid;
    int dq = (flat & 15) * 4;
    int t = (flat >> 4) & 2047;
    int h = flat >> 15;
    float v1[4], v2[4];
    if (t < 1024) {
      const float* p = past + ((size_t)h * 1024 + t) * 128;
      float4 a = *(const float4*)(p + dq);
      float4 c = *(const float4*)(p + 64 + dq);
      v1[0] = a.x; v1[1] = a.y; v1[2] = a.z; v1[3] = a.w;
      v2[0] = c.x; v2[1] = c.y; v2[2] = c.z; v2[3] = c.w;
    } else {
      size_t base = (size_t)(t - 1024) * 5120 + 4096 + h * 128;
      gsum4(gp, base + dq, v1);
      gsum4(gp, base + 64 + dq, v2);
    }
    float* o = outk + ((size_t)h * 2048 + t) * 128;
    *(float4*)(o + dq)      = make_float4(v1[0], v1[1], v1[2], v1[3]);
    *(float4*)(o + 64 + dq) = make_float4(v2[0], v2[1], v2[2], v2[3]);
    u16x4 k1, k2;
#pragma unroll
    for (int j = 0; j < 4; j++) {
      float2 cs = tab[t * 64 + dq + j];
      k1[j] = f2bf(v1[j] * cs.x - v2[j] * cs.y);
      k2[j] = f2bf(v2[j] * cs.x + v1[j] * cs.y);
    }
    unsigned short* ko = kr + ((size_t)h * 2048 + t) * 128;
    *(u16x4*)(ko + dq) = k1;
    *(u16x4*)(ko + 64 + dq) = k2;
  } else {                                  // ---- V: 64t x 128d tile ----
    __shared__ unsigned short lt[128][72];  // [d][t-local], +8 pad
    int vb = b - 2560;
    int h = vb >> 5;
    int tt = (vb & 31) * 64;                // tile start in t
#pragma unroll
    for (int pass = 0; pass < 8; ++pass) {
      int f2_ = pass * 256 + tid;
      int d = (f2_ & 31) * 4;
      int trow = f2_ >> 5;                  // 0..63
      int t = tt + trow;
      float4 val;
      if (t < 1024) {
        val = *(const float4*)(past + 524288 + ((size_t)h * 1024 + t) * 128 + d);
      } else {
        float tmp[4];
        gsum4(gp, (size_t)(t - 1024) * 5120 + 4608 + h * 128 + d, tmp);
        val = make_float4(tmp[0], tmp[1], tmp[2], tmp[3]);
      }
      *(float4*)(outv + ((size_t)h * 2048 + t) * 128 + d) = val;
      lt[d][trow]     = f2bf(val.x);
      lt[d + 1][trow] = f2bf(val.y);
      lt[d + 2][trow] = f2bf(val.z);
      lt[d + 3][trow] = f2bf(val.w);
    }
    __syncthreads();
#pragma unroll
    for (int pass = 0; pass < 4; ++pass) {
      int f3 = pass * 256 + tid;
      int d = f3 >> 3;                      // 0..127
      int tc = (f3 & 7) * 8;                // 0..56
      u16x8 o;
#pragma unroll
      for (int j = 0; j < 8; j++) o[j] = lt[d][tc + j];
      *(u16x8*)(vt + ((size_t)h * 128 + d) * 2048 + tt + tc) = o;
    }
  }
}

// ---------------- kernel 5: flash attention, 8-wave shared-KV (R10-identical) ---
__global__ __launch_bounds__(512) void k_attn8(
    const unsigned short* __restrict__ qr,  // [32][1024][128] (pre-scaled, log2)
    const unsigned short* __restrict__ kr,  // [4][2048][128] (RoPE'd)
    const unsigned short* __restrict__ vt,  // [4][128][2048]
    unsigned short* __restrict__ ctxb) {    // [1024][4096] bf16
  __shared__ unsigned short k_lds[2][64 * 128];
  __shared__ unsigned short v_lds[2][128 * 64];
  __shared__ unsigned short plds[8][640];
  const int bid = blockIdx.x;
  const int h = bid >> 3;
  const int c = bid & 7;
  const int kvh = h >> 3;
  const int tid = threadIdx.x;
  const int w = tid >> 6, l = tid & 63;
  const int lr = l & 15, lg = l >> 4;
  const int q0 = c * 128 + w * 16;
  const unsigned short* kh = kr + (size_t)kvh * 2048 * 128;
  const unsigned short* vh = vt + (size_t)kvh * 128 * 2048;

  u16x8 qf[4];
  {
    const unsigned short* qb = qr + ((size_t)(h * 1024 + q0 + lr)) * 128 + lg * 8;
#pragma unroll
    for (int ks = 0; ks < 4; ks++) qf[ks] = *(const u16x8*)(qb + ks * 32);
  }
  f32x4 acc[8];
#pragma unroll
  for (int i = 0; i < 8; i++) acc[i] = (f32x4){0.f, 0.f, 0.f, 0.f};
  float m_r = -1e30f, l_r = 0.f;

  const int limit = 1024 + q0 + lr;
  const int mylimit = 1024 + q0 + 15;
  const int T = 18 + 2 * c;

  auto stageK = [&](int buf, int kb) {
#pragma unroll
    for (int i = 0; i < 2; i++) {
      int loff = i * 8192 + tid * 16;
      int row = loff >> 8;
      int scb = (loff & 255) ^ ((row & 7) << 4);
      load_lds16((const char*)(kh + (size_t)(kb + row) * 128) + scb,
                 (char*)&k_lds[buf][0] + loff);
    }
  };
  auto stageV = [&](int buf, int kb) {
#pragma unroll
    for (int i = 0; i < 2; i++) {
      int loff = i * 8192 + tid * 16;
      int row = loff >> 7;
      int scb = (loff & 127) ^ ((row & 7) << 4);
      load_lds16((const char*)(vh + (size_t)row * 2048 + kb) + scb,
                 (char*)&v_lds[buf][0] + loff);
    }
  };

  stageK(0, 0); stageV(0, 0);
  __syncthreads();
  int cur = 0;
  for (int t = 0; t < T; t++) {
    if (t + 1 < T) { stageK(cur ^ 1, (t + 1) * 64); stageV(cur ^ 1, (t + 1) * 64); }
    if (t * 64 <= mylimit) {
#pragma unroll
      for (int kc = 0; kc < 2; kc++) {
        const int kb = t * 64 + kc * 32;
        if (kb > mylimit) continue;
        f32x4 s[2];
#pragma unroll
        for (int sub = 0; sub < 2; sub++) {
          f32x4 a = (f32x4){0.f, 0.f, 0.f, 0.f};
          const int key = kc * 32 + sub * 16 + lr;
          const int swz = (key & 7) << 4;
#pragma unroll
          for (int ks = 0; ks < 4; ks++) {
            int addr = key * 256 + ((ks * 64 + lg * 16) ^ swz);
            u16x8 kf = *(const u16x8*)((const char*)&k_lds[cur][0] + addr);
            mfma16x16x32(a, kf, qf[ks]);
          }
          s[sub] = a;
        }
        float v[8];
#pragma unroll
        for (int r = 0; r < 4; r++) { v[r] = s[0][r]; v[4 + r] = s[1][r]; }
        if (kb + 31 > 1024 + q0) {
          const int kbase = kb + lg * 4;
#pragma unroll
          for (int r = 0; r < 4; r++) {
            if (kbase + r > limit)      v[r]     = -1e30f;
            if (kbase + 16 + r > limit) v[4 + r] = -1e30f;
          }
        }
        float tmax = v[0];
#pragma unroll
        for (int j = 1; j < 8; j++) tmax = fmaxf(tmax, v[j]);
        tmax = fmaxf(tmax, __shfl_xor(tmax, 16));
        tmax = fmaxf(tmax, __shfl_xor(tmax, 32));
        if (!__all(tmax <= m_r + 11.5f)) {
          float mn = fmaxf(m_r, tmax);
          float corr = exp2f(m_r - mn);
          m_r = mn;
          l_r *= corr;
#pragma unroll
          for (int nt = 0; nt < 8; nt++)
#pragma unroll
            for (int r = 0; r < 4; r++) acc[nt][r] *= corr;
        }
        float p[8];
        float psum = 0.f;
#pragma unroll
        for (int j = 0; j < 8; j++) { p[j] = exp2f(v[j] - m_r); psum += p[j]; }
        psum += __shfl_xor(psum, 16);
        psum += __shfl_xor(psum, 32);
        l_r += psum;
        unsigned wds[4];
#pragma unroll
        for (int j = 0; j < 4; j++) {
          unsigned lo = __builtin_bit_cast(unsigned, p[2 * j]) + 0x8000u;
          unsigned hi = __builtin_bit_cast(unsigned, p[2 * j + 1]) + 0x8000u;
          wds[j] = (hi & 0xFFFF0000u) | (lo >> 16);
        }
        char* pb = (char*)&plds[w][0] + lr * 80 + lg * 8;
        *(uint2*)(pb)      = make_uint2(wds[0], wds[1]);
        *(uint2*)(pb + 32) = make_uint2(wds[2], wds[3]);
        asm volatile("s_waitcnt lgkmcnt(0)" ::: "memory");
        u16x8 pf = *(const u16x8*)&plds[w][lr * 40 + lg * 8];
#pragma unroll
        for (int nt = 0; nt < 8; nt++) {
          const int d = nt * 16 + lr;
          int addr = d * 128 + ((kc * 64 + lg * 16) ^ ((d & 7) << 4));
          u16x8 vf = *(const u16x8*)((const char*)&v_lds[cur][0] + addr);
          mfma16x16x32(acc[nt], vf, pf);
        }
      }
    }
    __syncthreads();
    cur ^= 1;
  }
  float inv = 1.0f / l_r;
  unsigned short* ob = ctxb + (size_t)(q0 + lr) * 4096 + h * 128 + lg * 4;
#pragma unroll
  for (int nt = 0; nt < 8; nt++) {
    u16x4 o = { f2bf(acc[nt][0] * inv), f2bf(acc[nt][1] * inv),
                f2bf(acc[nt][2] * inv), f2bf(acc[nt][3] * inv) };
    *(u16x4*)(ob + nt * 16) = o;
  }
}

// ---------------- launch ----------------
extern "C" void kernel_launch(void* const* d_in, const int* in_sizes, int n_in,
                              void* d_out, int out_size, void* d_ws, size_t ws_size,
                              hipStream_t stream) {
  (void)in_sizes; (void)n_in; (void)out_size; (void)ws_size;
  const float* hs   = (const float*)d_in[0];
  const float* past = (const float*)d_in[1];
  // d_in[2] attention_mask: pure causal, synthesized analytically
  const float* Wq = (const float*)d_in[3];
  const float* Wk = (const float*)d_in[4];
  const float* Wv = (const float*)d_in[5];
  const float* Wo = (const float*)d_in[6];

  float* out_attn = (float*)d_out;                 // [1024][4096]
  float* out_pk = out_attn + 4194304;              // [4][2048][128]
  float* out_pv = out_pk + 1048576;                // [4][2048][128]

  const size_t MB = 1048576;
  char* ws = (char*)d_ws;
  unsigned short* hs_bf   = (unsigned short*)(ws);              // 8 MB
  unsigned short* wqkv_bf = (unsigned short*)(ws + 8 * MB);     // 40 MB [5120][4096]
  unsigned short* wo_bf   = (unsigned short*)(ws + 48 * MB);    // 32 MB [4096][4096]
  float2*         tab     = (float2*)(ws + 100 * MB);           // 1 MB
  unsigned short* kr      = (unsigned short*)(ws + 101 * MB);   // 2 MB
  unsigned short* vt      = (unsigned short*)(ws + 103 * MB);   // 2 MB
  unsigned short* qr      = (unsigned short*)(ws + 105 * MB);   // 8 MB
  unsigned short* ctxb    = (unsigned short*)(ws + 113 * MB);   // 8 MB
  unsigned short* gp      = (unsigned short*)(ws + 128 * MB);   // 40 MB bf16 partials

  k_cvt_all<<<2048, 256, 0, stream>>>(hs, Wq, Wk, Wv, Wo, hs_bf, wqkv_bf, tab);

  dim3 g1(5120 / 128, 1024 / 128, 4);              // split-K=4: 1280 blocks
  k_gemm_bt<<<g1, 256, 0, stream>>>(hs_bf, wqkv_bf, gp, 1024, 5120, 4096, 1024);

  k_post<<<2688, 256, 0, stream>>>(past, gp, out_pk, out_pv, kr, vt, qr, tab);

  k_attn8<<<256, 512, 0, stream>>>(qr, kr, vt, ctxb);

  dim3 g2(4096 / 128, 1024 / 128, 4);              // split-K=4: 1024 blocks
  k_gemm_bt<<<g2, 256, 0, stream>>>(ctxb, wo_bf, gp, 1024, 4096, 4096, 1024);
  k_reduce4<<<2048, 256, 0, stream>>>((const u16x4*)gp, (float4*)out_attn,
                                      1048576, 1048576);
}